// Round 3
// baseline (727.313 us; speedup 1.0000x reference)
//
#include <hip/hip_runtime.h>
#include <math.h>

typedef unsigned short u16;
typedef __attribute__((ext_vector_type(8))) short s16x8;   // 8 bf16 (4 VGPRs) MFMA A/B frag
typedef __attribute__((ext_vector_type(4))) float f32x4;   // MFMA C/D frag

#define NB 16
#define NS 1024
#define NE 768
#define NH 12
#define ND 64
#define NF 3072
#define NBS (NB*NS)   // 16384 token rows
#define NBH (NB*NH)   // 192 (b,h) pairs

__device__ __forceinline__ u16 f2bf(float f){
  unsigned u = __float_as_uint(f);
  unsigned r = (u + 0x7fffu + ((u >> 16) & 1u)) >> 16;  // RNE
  return (u16)r;
}

__device__ __forceinline__ void gload16(const void* g, void* l){
  // async global->LDS, 16B per lane; LDS dest = wave-uniform base + lane*16
  __builtin_amdgcn_global_load_lds((const __attribute__((address_space(1))) void*)g,
                                   (__attribute__((address_space(3))) void*)l, 16, 0, 0);
}

// ---------------- weight packing: fp32 [K][N] -> bf16 [N][K] (B^T for GEMM) ---
__global__ __launch_bounds__(256) void pack_t(const float* __restrict__ W,
                                              u16* __restrict__ Wt, int N, int K){
  __shared__ u16 tile[64*72];
  const int tid = threadIdx.x;
  const int n0 = blockIdx.x*64, k0 = blockIdx.y*64;
  #pragma unroll
  for (int it = 0; it < 4; ++it){
    int c = it*256 + tid;
    int row = c >> 4, col = (c & 15) * 4;        // row = k-local, col = n-local
    float4 v = *(const float4*)(W + (size_t)(k0+row)*N + n0 + col);
    tile[row*72+col+0] = f2bf(v.x); tile[row*72+col+1] = f2bf(v.y);
    tile[row*72+col+2] = f2bf(v.z); tile[row*72+col+3] = f2bf(v.w);
  }
  __syncthreads();
  #pragma unroll
  for (int it = 0; it < 2; ++it){
    int c = it*256 + tid;
    int nr = c >> 3, kc = (c & 7) * 8;
    s16x8 val;
    #pragma unroll
    for (int j = 0; j < 8; ++j) val[j] = tile[(kc+j)*72 + nr];
    *(s16x8*)(Wt + (size_t)(n0+nr)*K + k0 + kc) = val;
  }
}

// Wq/Wk/Wv are [H,E,D]; pack into [2304][768] bf16 rows n = p*768 + h*64 + d.
__global__ __launch_bounds__(256) void pack_qkv(const float* __restrict__ Wq,
    const float* __restrict__ Wk, const float* __restrict__ Wv,
    const float* __restrict__ bq, const float* __restrict__ bk,
    const float* __restrict__ bv, u16* __restrict__ Wt, float* __restrict__ bias){
  __shared__ u16 tile[64*72];
  const int tid = threadIdx.x;
  const int n0 = blockIdx.x*64, e0 = blockIdx.y*64;
  const int p = n0 / NE, rr = n0 % NE, h = rr >> 6;   // 64-wide tile = one head
  const float* Wsrc = (p==0) ? Wq : ((p==1) ? Wk : Wv);
  #pragma unroll
  for (int it = 0; it < 4; ++it){
    int c = it*256 + tid;
    int row = c >> 4, col = (c & 15) * 4;        // row = e-local, col = d
    float4 v = *(const float4*)(Wsrc + ((size_t)h*NE + e0 + row)*ND + col);
    tile[row*72+col+0] = f2bf(v.x); tile[row*72+col+1] = f2bf(v.y);
    tile[row*72+col+2] = f2bf(v.z); tile[row*72+col+3] = f2bf(v.w);
  }
  __syncthreads();
  #pragma unroll
  for (int it = 0; it < 2; ++it){
    int c = it*256 + tid;
    int dr = c >> 3, ec = (c & 7) * 8;
    s16x8 val;
    #pragma unroll
    for (int j = 0; j < 8; ++j) val[j] = tile[(ec+j)*72 + dr];
    *(s16x8*)(Wt + (size_t)(n0+dr)*NE + e0 + ec) = val;
  }
  if (e0 == 0 && tid < 64){
    const float* bsrc = (p==0) ? bq : ((p==1) ? bk : bv);
    bias[n0 + tid] = bsrc[rr + tid];
  }
}

// ---------------- LayerNorm: fp32 in -> bf16 out (row = 768) -----------------
__global__ __launch_bounds__(256) void ln_bf16(const float* __restrict__ x,
    const float* __restrict__ g, const float* __restrict__ b, u16* __restrict__ out){
  __shared__ float red[4];
  const int row = blockIdx.x, tid = threadIdx.x;
  const float* xr = x + (size_t)row*NE;
  float v0 = xr[tid], v1 = xr[tid+256], v2 = xr[tid+512];
  float s = v0 + v1 + v2;
  #pragma unroll
  for (int off = 32; off > 0; off >>= 1) s += __shfl_down(s, off);
  if ((tid & 63) == 0) red[tid >> 6] = s;
  __syncthreads();
  float mu = (red[0]+red[1]+red[2]+red[3]) * (1.f/NE);
  float d0 = v0-mu, d1 = v1-mu, d2 = v2-mu;
  float q = d0*d0 + d1*d1 + d2*d2;
  #pragma unroll
  for (int off = 32; off > 0; off >>= 1) q += __shfl_down(q, off);
  __syncthreads();
  if ((tid & 63) == 0) red[tid >> 6] = q;
  __syncthreads();
  float rs = rsqrtf((red[0]+red[1]+red[2]+red[3]) * (1.f/NE) + 1e-5f);
  u16* orow = out + (size_t)row*NE;
  orow[tid]     = f2bf(d0*rs*g[tid]     + b[tid]);
  orow[tid+256] = f2bf(d1*rs*g[tid+256] + b[tid+256]);
  orow[tid+512] = f2bf(d2*rs*g[tid+512] + b[tid+512]);
}

// final: out = x1 + LN(f2) (in-place on x1 == d_out, fp32)
__global__ __launch_bounds__(256) void ln_add_out(const float* __restrict__ f2,
    const float* __restrict__ g, const float* __restrict__ b, float* __restrict__ x1){
  __shared__ float red[4];
  const int row = blockIdx.x, tid = threadIdx.x;
  const float* xr = f2 + (size_t)row*NE;
  float v0 = xr[tid], v1 = xr[tid+256], v2 = xr[tid+512];
  float s = v0 + v1 + v2;
  #pragma unroll
  for (int off = 32; off > 0; off >>= 1) s += __shfl_down(s, off);
  if ((tid & 63) == 0) red[tid >> 6] = s;
  __syncthreads();
  float mu = (red[0]+red[1]+red[2]+red[3]) * (1.f/NE);
  float d0 = v0-mu, d1 = v1-mu, d2 = v2-mu;
  float q = d0*d0 + d1*d1 + d2*d2;
  #pragma unroll
  for (int off = 32; off > 0; off >>= 1) q += __shfl_down(q, off);
  __syncthreads();
  if ((tid & 63) == 0) red[tid >> 6] = q;
  __syncthreads();
  float rs = rsqrtf((red[0]+red[1]+red[2]+red[3]) * (1.f/NE) + 1e-5f);
  float* orow = x1 + (size_t)row*NE;
  orow[tid]     += d0*rs*g[tid]     + b[tid];
  orow[tid+256] += d1*rs*g[tid+256] + b[tid+256];
  orow[tid+512] += d2*rs*g[tid+512] + b[tid+512];
}

// ---------------- generic bf16 MFMA GEMM: C[M][N] = A[M][K] * Bt[N][K]^T -----
// 128x128 tile, 4 waves (2x2), BK=32, global_load_lds staging (m97 structure).
// EPI: 0 = QKV scatter (+bias), 1 = +bias+residual fp32, 2 = +bias GELU bf16,
//      3 = +bias fp32
template<int EPI>
__global__ __launch_bounds__(256, 2)
void gemm_bt(const u16* __restrict__ A, const u16* __restrict__ Bt,
             const float* __restrict__ bias, const float* __restrict__ resid,
             float* __restrict__ outF, u16* __restrict__ outU,
             u16* __restrict__ oq, u16* __restrict__ ok, u16* __restrict__ ov,
             int M, int N, int K)
{
  __shared__ u16 As[128*32];
  __shared__ u16 Bs[128*32];
  const int tid = threadIdx.x;
  const int lane = tid & 63, wv = tid >> 6;
  const int wm = wv >> 1, wn = wv & 1;
  const int r = lane & 15, g4 = lane >> 4;
  const int m0 = blockIdx.y*128, n0 = blockIdx.x*128;

  f32x4 acc[4][4] = {};

  for (int kt = 0; kt < K; kt += 32) {
    __syncthreads();
    #pragma unroll
    for (int it = 0; it < 2; ++it) {
      int c = it*256 + tid;
      int row = c >> 2, kc = (c & 3) << 3;         // 4 chunks of 8 bf16 per row
      gload16(A  + (size_t)(m0+row)*K + kt + kc, As + (size_t)(it*256 + wv*64)*8);
      gload16(Bt + (size_t)(n0+row)*K + kt + kc, Bs + (size_t)(it*256 + wv*64)*8);
    }
    __syncthreads();
    s16x8 aF[4], bF[4];
    #pragma unroll
    for (int mi = 0; mi < 4; ++mi)
      aF[mi] = *(const s16x8*)(As + (wm*64 + mi*16 + r)*32 + g4*8);
    #pragma unroll
    for (int ni = 0; ni < 4; ++ni)
      bF[ni] = *(const s16x8*)(Bs + (wn*64 + ni*16 + r)*32 + g4*8);
    #pragma unroll
    for (int mi = 0; mi < 4; ++mi)
      #pragma unroll
      for (int ni = 0; ni < 4; ++ni)
        acc[mi][ni] = __builtin_amdgcn_mfma_f32_16x16x32_bf16(aF[mi], bF[ni], acc[mi][ni], 0, 0, 0);
  }

  const int colb = n0 + wn*64, rowb = m0 + wm*64;
  #pragma unroll
  for (int mi = 0; mi < 4; ++mi) {
    #pragma unroll
    for (int ni = 0; ni < 4; ++ni) {
      const int col = colb + ni*16 + r;
      const float bv = bias[col];
      #pragma unroll
      for (int i = 0; i < 4; ++i) {
        const int row = rowb + mi*16 + g4*4 + i;   // C/D: col=lane&15, row=(lane>>4)*4+i
        float v = acc[mi][ni][i] + bv;
        if (EPI == 0) {
          int p = col / NE, rr2 = col % NE;
          int hh = rr2 >> 6, d = rr2 & 63;
          int bb = row >> 10, ss = row & (NS-1);
          size_t idx = (((size_t)(bb*NH + hh))*NS + ss)*ND + d;
          u16 val = f2bf(v);
          if (p == 0) oq[idx] = val;
          else if (p == 1) ok[idx] = val;
          else ov[idx] = val;
        } else if (EPI == 1) {
          size_t idx = (size_t)row*NE + col;
          outF[idx] = resid[idx] + v;
        } else if (EPI == 2) {
          float ge = 0.5f * v * (1.0f + erff(v * 0.70710678118654752f));
          outU[(size_t)row*NF + col] = f2bf(ge);
        } else {
          outF[(size_t)row*NE + col] = v;
        }
      }
    }
  }
}

// ---------------- v [BH][S][D] -> vT [BH][D][S] (bf16) -----------------------
__global__ __launch_bounds__(256) void transpose_v(const u16* __restrict__ v,
                                                   u16* __restrict__ vT){
  __shared__ u16 tile[64*80];
  const int tid = threadIdx.x;
  const int t0 = blockIdx.x*64, bh = blockIdx.y;
  const u16* src = v + ((size_t)bh*NS + t0)*ND;
  #pragma unroll
  for (int it = 0; it < 2; ++it){
    int c = it*256 + tid;
    int row = c >> 3, col = (c & 7) * 8;
    *(s16x8*)(tile + row*80 + col) = *(const s16x8*)(src + (size_t)row*ND + col);
  }
  __syncthreads();
  u16* dst = vT + (size_t)bh*ND*NS + t0;
  #pragma unroll
  for (int it = 0; it < 2; ++it){
    int c = it*256 + tid;
    int d = c >> 3, tc = (c & 7) * 8;
    s16x8 val;
    #pragma unroll
    for (int j = 0; j < 8; ++j) val[j] = tile[(tc+j)*80 + d];
    *(s16x8*)(dst + (size_t)d*NS + tc) = val;
  }
}

// ---------------- flash attention (causal), 64 q-rows/block, 4 waves ---------
// v2: stride 72 (2-way banks), double-buffered K/V with reg staging (T14),
//     ONE barrier per K-tile, setprio around MFMA clusters (T5).
__device__ __forceinline__ void load_kv(const u16* __restrict__ kbase,
                                        const u16* __restrict__ vbase,
                                        int kt0, int tid, s16x8* kr, s16x8* vr){
  #pragma unroll
  for (int it = 0; it < 2; ++it){
    int c = it*256 + tid;
    int rowi = c >> 3, coli = (c & 7) * 8;
    kr[it] = *(const s16x8*)(kbase + (size_t)(kt0+rowi)*ND + coli);
    vr[it] = *(const s16x8*)(vbase + (size_t)rowi*NS + kt0 + coli);
  }
}

__global__ __launch_bounds__(256, 2)
void attn(const u16* __restrict__ q, const u16* __restrict__ k,
          const u16* __restrict__ vT, u16* __restrict__ o)
{
  __shared__ u16 Ks[2][64*72];   // K tile  [t][d] (stride 72: 2-way banks, 16B aligned)
  __shared__ u16 Vs[2][64*72];   // V^T tile [d][t]
  __shared__ u16 Ps[64*72];      // P tile  [s][t] bf16 (same-wave use only)
  const int tid = threadIdx.x, lane = tid & 63, w = tid >> 6;
  const int r = lane & 15, g4 = lane >> 4;
  const int qt = blockIdx.x, bh = blockIdx.y;
  const int qs0 = qt*64;
  const int bb = bh / NH, hh = bh % NH;

  const u16* qrow = q + ((size_t)bh*NS + qs0 + w*16 + r)*ND;
  s16x8 qf0 = *(const s16x8*)(qrow + g4*8);
  s16x8 qf1 = *(const s16x8*)(qrow + 32 + g4*8);

  f32x4 oacc[4] = {};
  float mrow[4], lrow[4];
  #pragma unroll
  for (int i = 0; i < 4; ++i){ mrow[i] = -INFINITY; lrow[i] = 0.f; }

  const u16* kbase = k  + (size_t)bh*NS*ND;
  const u16* vbase = vT + (size_t)bh*ND*NS;
  const int nt = qs0/64 + 1;

  s16x8 kr[2], vr[2];
  load_kv(kbase, vbase, 0, tid, kr, vr);   // prologue: tile 0 -> regs

  int cur = 0;
  for (int t = 0; t < nt; ++t) {
    const int kt0 = t*64;
    // write staged regs to LDS[cur] (vmcnt wait auto-inserted before use)
    #pragma unroll
    for (int it = 0; it < 2; ++it){
      int c = it*256 + tid;
      int rowi = c >> 3, coli = (c & 7) * 8;
      *(s16x8*)(&Ks[cur][rowi*72 + coli]) = kr[it];
      *(s16x8*)(&Vs[cur][rowi*72 + coli]) = vr[it];
    }
    __syncthreads();
    if (t+1 < nt) load_kv(kbase, vbase, kt0+64, tid, kr, vr);  // fly under compute

    // scores: wave's 16 s-rows x 64 t-cols
    f32x4 sc[4];
    __builtin_amdgcn_s_setprio(1);
    #pragma unroll
    for (int ni = 0; ni < 4; ++ni) {
      s16x8 kf0 = *(const s16x8*)(&Ks[cur][(ni*16+r)*72 + g4*8]);
      s16x8 kf1 = *(const s16x8*)(&Ks[cur][(ni*16+r)*72 + 32 + g4*8]);
      f32x4 tacc = {};
      tacc = __builtin_amdgcn_mfma_f32_16x16x32_bf16(qf0, kf0, tacc, 0, 0, 0);
      tacc = __builtin_amdgcn_mfma_f32_16x16x32_bf16(qf1, kf1, tacc, 0, 0, 0);
      sc[ni] = tacc;
    }
    __builtin_amdgcn_s_setprio(0);

    const bool diag = (kt0 == qs0);
    float mx[4];
    #pragma unroll
    for (int i = 0; i < 4; ++i) mx[i] = -INFINITY;
    #pragma unroll
    for (int ni = 0; ni < 4; ++ni)
      #pragma unroll
      for (int i = 0; i < 4; ++i) {
        float v = sc[ni][i] * 0.125f;              // 1/sqrt(64)
        if (diag && (kt0 + ni*16 + r > qs0 + w*16 + g4*4 + i)) v = -INFINITY;
        sc[ni][i] = v;
        mx[i] = fmaxf(mx[i], v);
      }
    #pragma unroll
    for (int i = 0; i < 4; ++i) {
      #pragma unroll
      for (int off = 1; off < 16; off <<= 1) mx[i] = fmaxf(mx[i], __shfl_xor(mx[i], off));
    }
    float corr[4], psum[4];
    #pragma unroll
    for (int i = 0; i < 4; ++i) {
      float mn = fmaxf(mrow[i], mx[i]);
      corr[i] = __expf(mrow[i] - mn);
      mrow[i] = mn;
      psum[i] = 0.f;
    }
    #pragma unroll
    for (int ni = 0; ni < 4; ++ni)
      #pragma unroll
      for (int i = 0; i < 4; ++i) {
        float p = __expf(sc[ni][i] - mrow[i]);
        psum[i] += p;
        Ps[(w*16 + g4*4 + i)*72 + ni*16 + r] = f2bf(p);
      }
    #pragma unroll
    for (int i = 0; i < 4; ++i) {
      #pragma unroll
      for (int off = 1; off < 16; off <<= 1) psum[i] += __shfl_xor(psum[i], off);
      lrow[i] = lrow[i]*corr[i] + psum[i];
    }
    #pragma unroll
    for (int di = 0; di < 4; ++di)
      #pragma unroll
      for (int i = 0; i < 4; ++i) oacc[di][i] *= corr[i];
    // PV (wave reads only its own 16 Ps rows; same-wave in-order LDS dep)
    __builtin_amdgcn_s_setprio(1);
    #pragma unroll
    for (int kk = 0; kk < 2; ++kk) {
      s16x8 pf = *(const s16x8*)(&Ps[(w*16 + r)*72 + kk*32 + g4*8]);
      #pragma unroll
      for (int di = 0; di < 4; ++di) {
        s16x8 vf = *(const s16x8*)(&Vs[cur][(di*16+r)*72 + kk*32 + g4*8]);
        oacc[di] = __builtin_amdgcn_mfma_f32_16x16x32_bf16(pf, vf, oacc[di], 0, 0, 0);
      }
    }
    __builtin_amdgcn_s_setprio(0);
    cur ^= 1;
  }

  #pragma unroll
  for (int i = 0; i < 4; ++i) {
    float inv = 1.f / lrow[i];
    int s = qs0 + w*16 + g4*4 + i;
    u16* orow = o + ((size_t)(bb*NS + s))*NE + hh*ND;
    #pragma unroll
    for (int di = 0; di < 4; ++di)
      orow[di*16 + r] = f2bf(oacc[di][i] * inv);
  }
}

// ---------------- launch ------------------------------------------------------
extern "C" void kernel_launch(void* const* d_in, const int* in_sizes, int n_in,
                              void* d_out, int out_size, void* d_ws, size_t ws_size,
                              hipStream_t stream)
{
  const float* x   = (const float*)d_in[0];
  const float* Wq  = (const float*)d_in[1];
  const float* bq  = (const float*)d_in[2];
  const float* Wk  = (const float*)d_in[3];
  const float* bk  = (const float*)d_in[4];
  const float* Wv  = (const float*)d_in[5];
  const float* bv  = (const float*)d_in[6];
  const float* Wp  = (const float*)d_in[7];
  const float* bp  = (const float*)d_in[8];
  const float* g1  = (const float*)d_in[9];
  const float* b1n = (const float*)d_in[10];
  const float* g2  = (const float*)d_in[11];
  const float* b2n = (const float*)d_in[12];
  const float* W1  = (const float*)d_in[13];
  const float* b1f = (const float*)d_in[14];
  const float* W2  = (const float*)d_in[15];
  const float* b2f = (const float*)d_in[16];
  const float* gf  = (const float*)d_in[17];
  const float* bf  = (const float*)d_in[18];

  char* ws = (char*)d_ws;
  u16*   WqkvT = (u16*)(ws + 0);           // 2304*768 bf16
  u16*   WpT   = (u16*)(ws + 3538944);     // 768*768
  u16*   W1T   = (u16*)(ws + 4718592);     // 3072*768
  u16*   W2T   = (u16*)(ws + 9437184);     // 768*3072
  float* qkvb  = (float*)(ws + 14155776);  // 2304 fp32
  u16*   hbuf  = (u16*)(ws + 14164992);    // h (LN1), later o
  u16*   qbuf  = (u16*)(ws + 39330816);    // q, later h2
  u16*   kbuf  = (u16*)(ws + 64496640);    // k, later f2 low half
  u16*   vbuf  = (u16*)(ws + 89662464);    // v, later f2 high half
  u16*   vTbuf = (u16*)(ws + 114828288);   // v^T, dead after attn
  const size_t base_end = 139994112;       // end of vTbuf
  float* f2    = (float*)kbuf;             // 16384*768 fp32 (aliases k+v, both dead)
  float* x1    = (float*)d_out;            // x + attn proj (fp32), finalized in place

  // f1 (GELU out, bf16 [M][3072]) placement: full-size after vTbuf if ws
  // allows, else alias the dead vbuf+vTbuf region and chunk the FFN over
  // token rows (multiples of 128). Deterministic in ws_size -> capture-safe.
  const size_t f1_full = (size_t)NBS * NF * 2;   // 100,663,296
  u16* f1buf;
  int mc;                                         // rows per FFN chunk
  if (ws_size >= base_end + f1_full) {
    f1buf = (u16*)(ws + base_end);
    mc = NBS;
  } else {
    f1buf = vbuf;                                 // [89.7M, 140M) = 50.3MB free at FFN time
    size_t cap = (ws_size < base_end ? ws_size : base_end) - 89662464;
    mc = (int)(cap / ((size_t)NF * 2)) / 128 * 128;
    if (mc <= 0) mc = 128;                        // ws hopelessly small; best effort
    if (mc > NBS) mc = NBS;
  }

  // weight packing (weights re-poisoned every call -> repack every call)
  pack_qkv<<<dim3(36, 12), 256, 0, stream>>>(Wq, Wk, Wv, bq, bk, bv, WqkvT, qkvb);
  pack_t  <<<dim3(NE/64, NE/64), 256, 0, stream>>>(Wp, WpT, NE, NE);
  pack_t  <<<dim3(NF/64, NE/64), 256, 0, stream>>>(W1, W1T, NF, NE);
  pack_t  <<<dim3(NE/64, NF/64), 256, 0, stream>>>(W2, W2T, NE, NF);

  ln_bf16<<<NBS, 256, 0, stream>>>(x, g1, b1n, hbuf);
  gemm_bt<0><<<dim3(2304/128, NBS/128), 256, 0, stream>>>(hbuf, WqkvT, qkvb, nullptr,
      nullptr, nullptr, qbuf, kbuf, vbuf, NBS, 2304, NE);
  transpose_v<<<dim3(NS/64, NBH), 256, 0, stream>>>(vbuf, vTbuf);
  attn<<<dim3(NS/64, NBH), 256, 0, stream>>>(qbuf, kbuf, vTbuf, hbuf);
  gemm_bt<1><<<dim3(NE/128, NBS/128), 256, 0, stream>>>(hbuf, WpT, bp, x,
      x1, nullptr, nullptr, nullptr, nullptr, NBS, NE, NE);
  ln_bf16<<<NBS, 256, 0, stream>>>(x1, g2, b2n, qbuf);
  for (int r0 = 0; r0 < NBS; r0 += mc) {
    int m = (NBS - r0 < mc) ? (NBS - r0) : mc;
    gemm_bt<2><<<dim3(NF/128, m/128), 256, 0, stream>>>(qbuf + (size_t)r0*NE, W1T, b1f,
        nullptr, nullptr, f1buf, nullptr, nullptr, nullptr, m, NF, NE);
    gemm_bt<3><<<dim3(NE/128, m/128), 256, 0, stream>>>(f1buf, W2T, b2f, nullptr,
        f2 + (size_t)r0*NE, nullptr, nullptr, nullptr, nullptr, m, NE, NF);
  }
  ln_add_out<<<NBS, 256, 0, stream>>>(f2, gf, bf, x1);
}

// Round 4
// 707.467 us; speedup vs baseline: 1.0281x; 1.0281x over previous
//
#include <hip/hip_runtime.h>
#include <math.h>

typedef unsigned short u16;
typedef __attribute__((ext_vector_type(8))) short s16x8;   // 8 bf16 (4 VGPRs) MFMA A/B frag
typedef __attribute__((ext_vector_type(4))) float f32x4;   // MFMA C/D frag

#define NB 16
#define NS 1024
#define NE 768
#define NH 12
#define ND 64
#define NF 3072
#define NBS (NB*NS)   // 16384 token rows
#define NBH (NB*NH)   // 192 (b,h) pairs

__device__ __forceinline__ u16 f2bf(float f){
  unsigned u = __float_as_uint(f);
  unsigned r = (u + 0x7fffu + ((u >> 16) & 1u)) >> 16;  // RNE
  return (u16)r;
}

__device__ __forceinline__ void gload16(const void* g, void* l){
  // async global->LDS, 16B per lane; LDS dest = wave-uniform base + lane*16
  __builtin_amdgcn_global_load_lds((const __attribute__((address_space(1))) void*)g,
                                   (__attribute__((address_space(3))) void*)l, 16, 0, 0);
}

// ---------------- weight packing: fp32 [K][N] -> bf16 [N][K] (B^T for GEMM) ---
__global__ __launch_bounds__(256) void pack_t(const float* __restrict__ W,
                                              u16* __restrict__ Wt, int N, int K){
  __shared__ u16 tile[64*72];
  const int tid = threadIdx.x;
  const int n0 = blockIdx.x*64, k0 = blockIdx.y*64;
  #pragma unroll
  for (int it = 0; it < 4; ++it){
    int c = it*256 + tid;
    int row = c >> 4, col = (c & 15) * 4;        // row = k-local, col = n-local
    float4 v = *(const float4*)(W + (size_t)(k0+row)*N + n0 + col);
    tile[row*72+col+0] = f2bf(v.x); tile[row*72+col+1] = f2bf(v.y);
    tile[row*72+col+2] = f2bf(v.z); tile[row*72+col+3] = f2bf(v.w);
  }
  __syncthreads();
  #pragma unroll
  for (int it = 0; it < 2; ++it){
    int c = it*256 + tid;
    int nr = c >> 3, kc = (c & 7) * 8;
    s16x8 val;
    #pragma unroll
    for (int j = 0; j < 8; ++j) val[j] = tile[(kc+j)*72 + nr];
    *(s16x8*)(Wt + (size_t)(n0+nr)*K + k0 + kc) = val;
  }
}

// Wq/Wk/Wv are [H,E,D]; pack into [2304][768] bf16 rows n = p*768 + h*64 + d.
__global__ __launch_bounds__(256) void pack_qkv(const float* __restrict__ Wq,
    const float* __restrict__ Wk, const float* __restrict__ Wv,
    const float* __restrict__ bq, const float* __restrict__ bk,
    const float* __restrict__ bv, u16* __restrict__ Wt, float* __restrict__ bias){
  __shared__ u16 tile[64*72];
  const int tid = threadIdx.x;
  const int n0 = blockIdx.x*64, e0 = blockIdx.y*64;
  const int p = n0 / NE, rr = n0 % NE, h = rr >> 6;   // 64-wide tile = one head
  const float* Wsrc = (p==0) ? Wq : ((p==1) ? Wk : Wv);
  #pragma unroll
  for (int it = 0; it < 4; ++it){
    int c = it*256 + tid;
    int row = c >> 4, col = (c & 15) * 4;        // row = e-local, col = d
    float4 v = *(const float4*)(Wsrc + ((size_t)h*NE + e0 + row)*ND + col);
    tile[row*72+col+0] = f2bf(v.x); tile[row*72+col+1] = f2bf(v.y);
    tile[row*72+col+2] = f2bf(v.z); tile[row*72+col+3] = f2bf(v.w);
  }
  __syncthreads();
  #pragma unroll
  for (int it = 0; it < 2; ++it){
    int c = it*256 + tid;
    int dr = c >> 3, ec = (c & 7) * 8;
    s16x8 val;
    #pragma unroll
    for (int j = 0; j < 8; ++j) val[j] = tile[(ec+j)*72 + dr];
    *(s16x8*)(Wt + (size_t)(n0+dr)*NE + e0 + ec) = val;
  }
  if (e0 == 0 && tid < 64){
    const float* bsrc = (p==0) ? bq : ((p==1) ? bk : bv);
    bias[n0 + tid] = bsrc[rr + tid];
  }
}

// ---------------- LayerNorm: fp32 in -> bf16 out (row = 768) -----------------
__global__ __launch_bounds__(256) void ln_bf16(const float* __restrict__ x,
    const float* __restrict__ g, const float* __restrict__ b, u16* __restrict__ out){
  __shared__ float red[4];
  const int row = blockIdx.x, tid = threadIdx.x;
  const float* xr = x + (size_t)row*NE;
  float v0 = xr[tid], v1 = xr[tid+256], v2 = xr[tid+512];
  float s = v0 + v1 + v2;
  #pragma unroll
  for (int off = 32; off > 0; off >>= 1) s += __shfl_down(s, off);
  if ((tid & 63) == 0) red[tid >> 6] = s;
  __syncthreads();
  float mu = (red[0]+red[1]+red[2]+red[3]) * (1.f/NE);
  float d0 = v0-mu, d1 = v1-mu, d2 = v2-mu;
  float q = d0*d0 + d1*d1 + d2*d2;
  #pragma unroll
  for (int off = 32; off > 0; off >>= 1) q += __shfl_down(q, off);
  __syncthreads();
  if ((tid & 63) == 0) red[tid >> 6] = q;
  __syncthreads();
  float rs = rsqrtf((red[0]+red[1]+red[2]+red[3]) * (1.f/NE) + 1e-5f);
  u16* orow = out + (size_t)row*NE;
  orow[tid]     = f2bf(d0*rs*g[tid]     + b[tid]);
  orow[tid+256] = f2bf(d1*rs*g[tid+256] + b[tid+256]);
  orow[tid+512] = f2bf(d2*rs*g[tid+512] + b[tid+512]);
}

// final: out = x1 + LN(f2) (in-place on x1 == d_out, fp32)
__global__ __launch_bounds__(256) void ln_add_out(const float* __restrict__ f2,
    const float* __restrict__ g, const float* __restrict__ b, float* __restrict__ x1){
  __shared__ float red[4];
  const int row = blockIdx.x, tid = threadIdx.x;
  const float* xr = f2 + (size_t)row*NE;
  float v0 = xr[tid], v1 = xr[tid+256], v2 = xr[tid+512];
  float s = v0 + v1 + v2;
  #pragma unroll
  for (int off = 32; off > 0; off >>= 1) s += __shfl_down(s, off);
  if ((tid & 63) == 0) red[tid >> 6] = s;
  __syncthreads();
  float mu = (red[0]+red[1]+red[2]+red[3]) * (1.f/NE);
  float d0 = v0-mu, d1 = v1-mu, d2 = v2-mu;
  float q = d0*d0 + d1*d1 + d2*d2;
  #pragma unroll
  for (int off = 32; off > 0; off >>= 1) q += __shfl_down(q, off);
  __syncthreads();
  if ((tid & 63) == 0) red[tid >> 6] = q;
  __syncthreads();
  float rs = rsqrtf((red[0]+red[1]+red[2]+red[3]) * (1.f/NE) + 1e-5f);
  float* orow = x1 + (size_t)row*NE;
  orow[tid]     += d0*rs*g[tid]     + b[tid];
  orow[tid+256] += d1*rs*g[tid+256] + b[tid+256];
  orow[tid+512] += d2*rs*g[tid+512] + b[tid+512];
}

// ---------------- generic bf16 MFMA GEMM: C[M][N] = A[M][K] * Bt[N][K]^T -----
// 128x128 tile, 4 waves (2x2), BK=32, global_load_lds staging (m97 structure).
// EPI: 0 = QKV scatter (+bias, K pre-scaled by log2e/sqrt(D)), 1 = +bias+resid
//      fp32, 2 = +bias GELU bf16, 3 = +bias fp32
template<int EPI>
__global__ __launch_bounds__(256, 2)
void gemm_bt(const u16* __restrict__ A, const u16* __restrict__ Bt,
             const float* __restrict__ bias, const float* __restrict__ resid,
             float* __restrict__ outF, u16* __restrict__ outU,
             u16* __restrict__ oq, u16* __restrict__ ok, u16* __restrict__ ov,
             int M, int N, int K)
{
  __shared__ u16 As[128*32];
  __shared__ u16 Bs[128*32];
  const int tid = threadIdx.x;
  const int lane = tid & 63, wv = tid >> 6;
  const int wm = wv >> 1, wn = wv & 1;
  const int r = lane & 15, g4 = lane >> 4;
  const int m0 = blockIdx.y*128, n0 = blockIdx.x*128;

  f32x4 acc[4][4] = {};

  for (int kt = 0; kt < K; kt += 32) {
    __syncthreads();
    #pragma unroll
    for (int it = 0; it < 2; ++it) {
      int c = it*256 + tid;
      int row = c >> 2, kc = (c & 3) << 3;         // 4 chunks of 8 bf16 per row
      gload16(A  + (size_t)(m0+row)*K + kt + kc, As + (size_t)(it*256 + wv*64)*8);
      gload16(Bt + (size_t)(n0+row)*K + kt + kc, Bs + (size_t)(it*256 + wv*64)*8);
    }
    __syncthreads();
    s16x8 aF[4], bF[4];
    #pragma unroll
    for (int mi = 0; mi < 4; ++mi)
      aF[mi] = *(const s16x8*)(As + (wm*64 + mi*16 + r)*32 + g4*8);
    #pragma unroll
    for (int ni = 0; ni < 4; ++ni)
      bF[ni] = *(const s16x8*)(Bs + (wn*64 + ni*16 + r)*32 + g4*8);
    #pragma unroll
    for (int mi = 0; mi < 4; ++mi)
      #pragma unroll
      for (int ni = 0; ni < 4; ++ni)
        acc[mi][ni] = __builtin_amdgcn_mfma_f32_16x16x32_bf16(aF[mi], bF[ni], acc[mi][ni], 0, 0, 0);
  }

  const int colb = n0 + wn*64, rowb = m0 + wm*64;
  #pragma unroll
  for (int mi = 0; mi < 4; ++mi) {
    #pragma unroll
    for (int ni = 0; ni < 4; ++ni) {
      const int col = colb + ni*16 + r;
      const float bv = bias[col];
      #pragma unroll
      for (int i = 0; i < 4; ++i) {
        const int row = rowb + mi*16 + g4*4 + i;   // C/D: col=lane&15, row=(lane>>4)*4+i
        float v = acc[mi][ni][i] + bv;
        if (EPI == 0) {
          int p = col / NE, rr2 = col % NE;
          int hh = rr2 >> 6, d = rr2 & 63;
          int bb = row >> 10, ss = row & (NS-1);
          size_t idx = (((size_t)(bb*NH + hh))*NS + ss)*ND + d;
          if (p == 1) v *= 0.18033688011112042f;   // log2(e)/sqrt(D) folded into K
          u16 val = f2bf(v);
          if (p == 0) oq[idx] = val;
          else if (p == 1) ok[idx] = val;
          else ov[idx] = val;
        } else if (EPI == 1) {
          size_t idx = (size_t)row*NE + col;
          outF[idx] = resid[idx] + v;
        } else if (EPI == 2) {
          float ge = 0.5f * v * (1.0f + erff(v * 0.70710678118654752f));
          outU[(size_t)row*NF + col] = f2bf(ge);
        } else {
          outF[(size_t)row*NE + col] = v;
        }
      }
    }
  }
}

// ---------------- v [BH][S][D] -> vT [BH][D][S] (bf16) -----------------------
__global__ __launch_bounds__(256) void transpose_v(const u16* __restrict__ v,
                                                   u16* __restrict__ vT){
  __shared__ u16 tile[64*80];
  const int tid = threadIdx.x;
  const int t0 = blockIdx.x*64, bh = blockIdx.y;
  const u16* src = v + ((size_t)bh*NS + t0)*ND;
  #pragma unroll
  for (int it = 0; it < 2; ++it){
    int c = it*256 + tid;
    int row = c >> 3, col = (c & 7) * 8;
    *(s16x8*)(tile + row*80 + col) = *(const s16x8*)(src + (size_t)row*ND + col);
  }
  __syncthreads();
  u16* dst = vT + (size_t)bh*ND*NS + t0;
  #pragma unroll
  for (int it = 0; it < 2; ++it){
    int c = it*256 + tid;
    int d = c >> 3, tc = (c & 7) * 8;
    s16x8 val;
    #pragma unroll
    for (int j = 0; j < 8; ++j) val[j] = tile[(tc+j)*80 + d];
    *(s16x8*)(dst + (size_t)d*NS + tc) = val;
  }
}

// ---------------- flash attention (causal) -----------------------------------
// v3: 128 q-rows/block (two 64-row groups share each staged K/V tile),
//     4 waves, v1's measured-best LDS layout (stride 80, 2 barriers/tile),
//     exp2-domain softmax (scale folded into K), XCD-swizzled block order.
__global__ __launch_bounds__(256, 2)
void attn(const u16* __restrict__ q, const u16* __restrict__ k,
          const u16* __restrict__ vT, u16* __restrict__ o)
{
  __shared__ u16 Ks[64*80];   // K tile  [t][d]
  __shared__ u16 Vs[64*80];   // V^T tile [d][t]
  __shared__ u16 Ps[64*80];   // P tile  [s][t] bf16 (wave-private rows)
  const int tid = threadIdx.x, lane = tid & 63, w = tid >> 6;
  const int r = lane & 15, g4 = lane >> 4;
  // XCD swizzle: physical dispatch id -> logical (bh-major), 192-block chunks
  // per XCD so all 8 q-tiles of a (b,h) share one XCD's L2. 1536 % 8 == 0.
  const int phys = blockIdx.y * 8 + blockIdx.x;     // gridDim = (8, 192)
  const int logical = (phys & 7) * 192 + (phys >> 3);
  const int bh = logical >> 3, qt = logical & 7;
  const int qs0 = qt * 128;
  const int bb = bh / NH, hh = bh % NH;

  s16x8 qf[2][2];
  {
    const u16* qb = q + ((size_t)bh*NS + qs0 + w*16 + r)*ND;
    qf[0][0] = *(const s16x8*)(qb + g4*8);
    qf[0][1] = *(const s16x8*)(qb + 32 + g4*8);
    qf[1][0] = *(const s16x8*)(qb + (size_t)64*ND + g4*8);
    qf[1][1] = *(const s16x8*)(qb + (size_t)64*ND + 32 + g4*8);
  }

  f32x4 oacc[2][4] = {};
  float mrow[2][4], lrow[2][4];
  #pragma unroll
  for (int rg = 0; rg < 2; ++rg)
    #pragma unroll
    for (int i = 0; i < 4; ++i){ mrow[rg][i] = -INFINITY; lrow[rg][i] = 0.f; }

  const u16* kbase = k  + (size_t)bh*NS*ND;
  const u16* vbase = vT + (size_t)bh*ND*NS;
  const int nt = qs0/64 + 2;

  for (int t = 0; t < nt; ++t) {
    const int kt0 = t*64;
    __syncthreads();
    #pragma unroll
    for (int it = 0; it < 2; ++it) {
      int c = it*256 + tid;
      int rowi = c >> 3, coli = (c & 7) * 8;
      *(s16x8*)(Ks + rowi*80 + coli) = *(const s16x8*)(kbase + (size_t)(kt0+rowi)*ND + coli);
      *(s16x8*)(Vs + rowi*80 + coli) = *(const s16x8*)(vbase + (size_t)rowi*NS + kt0 + coli);
    }
    __syncthreads();

    #pragma unroll
    for (int rg = 0; rg < 2; ++rg) {
      const int rgb = qs0 + rg*64;           // rowgroup base
      if (kt0 > rgb) continue;               // fully masked (uniform branch)

      f32x4 sc[4];
      __builtin_amdgcn_s_setprio(1);
      #pragma unroll
      for (int ni = 0; ni < 4; ++ni) {
        s16x8 kf0 = *(const s16x8*)(Ks + (ni*16+r)*80 + g4*8);
        s16x8 kf1 = *(const s16x8*)(Ks + (ni*16+r)*80 + 32 + g4*8);
        f32x4 tacc = {};
        tacc = __builtin_amdgcn_mfma_f32_16x16x32_bf16(qf[rg][0], kf0, tacc, 0, 0, 0);
        tacc = __builtin_amdgcn_mfma_f32_16x16x32_bf16(qf[rg][1], kf1, tacc, 0, 0, 0);
        sc[ni] = tacc;
      }
      __builtin_amdgcn_s_setprio(0);

      float mx[4];
      #pragma unroll
      for (int i = 0; i < 4; ++i) mx[i] = mrow[rg][i];
      if (kt0 == rgb) {                       // diagonal tile: causal mask
        #pragma unroll
        for (int ni = 0; ni < 4; ++ni)
          #pragma unroll
          for (int i = 0; i < 4; ++i) {
            if (ni*16 + r > w*16 + g4*4 + i) sc[ni][i] = -INFINITY;
            mx[i] = fmaxf(mx[i], sc[ni][i]);
          }
      } else {
        #pragma unroll
        for (int ni = 0; ni < 4; ++ni)
          #pragma unroll
          for (int i = 0; i < 4; ++i) mx[i] = fmaxf(mx[i], sc[ni][i]);
      }
      #pragma unroll
      for (int i = 0; i < 4; ++i) {
        #pragma unroll
        for (int off = 1; off < 16; off <<= 1) mx[i] = fmaxf(mx[i], __shfl_xor(mx[i], off));
      }
      float corr[4], psum[4];
      #pragma unroll
      for (int i = 0; i < 4; ++i) {
        corr[i] = exp2f(mrow[rg][i] - mx[i]); // exp2(-inf)=0 on first tile
        mrow[rg][i] = mx[i];
        psum[i] = 0.f;
      }
      #pragma unroll
      for (int ni = 0; ni < 4; ++ni)
        #pragma unroll
        for (int i = 0; i < 4; ++i) {
          float p = exp2f(sc[ni][i] - mrow[rg][i]);   // scores already log2-scaled
          psum[i] += p;
          Ps[(w*16 + g4*4 + i)*80 + ni*16 + r] = f2bf(p);
        }
      #pragma unroll
      for (int i = 0; i < 4; ++i) {
        #pragma unroll
        for (int off = 1; off < 16; off <<= 1) psum[i] += __shfl_xor(psum[i], off);
        lrow[rg][i] = lrow[rg][i]*corr[i] + psum[i];
      }
      #pragma unroll
      for (int di = 0; di < 4; ++di)
        #pragma unroll
        for (int i = 0; i < 4; ++i) oacc[rg][di][i] *= corr[i];
      // PV (wave reads only its own 16 Ps rows; same-wave in-order LDS dep)
      __builtin_amdgcn_s_setprio(1);
      #pragma unroll
      for (int kk = 0; kk < 2; ++kk) {
        s16x8 pf = *(const s16x8*)(Ps + (w*16 + r)*80 + kk*32 + g4*8);
        #pragma unroll
        for (int di = 0; di < 4; ++di) {
          s16x8 vf = *(const s16x8*)(Vs + (di*16+r)*80 + kk*32 + g4*8);
          oacc[rg][di] = __builtin_amdgcn_mfma_f32_16x16x32_bf16(pf, vf, oacc[rg][di], 0, 0, 0);
        }
      }
      __builtin_amdgcn_s_setprio(0);
    }
  }

  #pragma unroll
  for (int rg = 0; rg < 2; ++rg)
    #pragma unroll
    for (int i = 0; i < 4; ++i) {
      float inv = 1.f / lrow[rg][i];
      int s = qs0 + rg*64 + w*16 + g4*4 + i;
      u16* orow = o + ((size_t)(bb*NS + s))*NE + hh*ND;
      #pragma unroll
      for (int di = 0; di < 4; ++di)
        orow[di*16 + r] = f2bf(oacc[rg][di][i] * inv);
    }
}

// ---------------- launch ------------------------------------------------------
extern "C" void kernel_launch(void* const* d_in, const int* in_sizes, int n_in,
                              void* d_out, int out_size, void* d_ws, size_t ws_size,
                              hipStream_t stream)
{
  const float* x   = (const float*)d_in[0];
  const float* Wq  = (const float*)d_in[1];
  const float* bq  = (const float*)d_in[2];
  const float* Wk  = (const float*)d_in[3];
  const float* bk  = (const float*)d_in[4];
  const float* Wv  = (const float*)d_in[5];
  const float* bv  = (const float*)d_in[6];
  const float* Wp  = (const float*)d_in[7];
  const float* bp  = (const float*)d_in[8];
  const float* g1  = (const float*)d_in[9];
  const float* b1n = (const float*)d_in[10];
  const float* g2  = (const float*)d_in[11];
  const float* b2n = (const float*)d_in[12];
  const float* W1  = (const float*)d_in[13];
  const float* b1f = (const float*)d_in[14];
  const float* W2  = (const float*)d_in[15];
  const float* b2f = (const float*)d_in[16];
  const float* gf  = (const float*)d_in[17];
  const float* bf  = (const float*)d_in[18];

  char* ws = (char*)d_ws;
  u16*   WqkvT = (u16*)(ws + 0);           // 2304*768 bf16
  u16*   WpT   = (u16*)(ws + 3538944);     // 768*768
  u16*   W1T   = (u16*)(ws + 4718592);     // 3072*768
  u16*   W2T   = (u16*)(ws + 9437184);     // 768*3072
  float* qkvb  = (float*)(ws + 14155776);  // 2304 fp32
  u16*   hbuf  = (u16*)(ws + 14164992);    // h (LN1), later o
  u16*   qbuf  = (u16*)(ws + 39330816);    // q, later h2
  u16*   kbuf  = (u16*)(ws + 64496640);    // k, later f2 low half
  u16*   vbuf  = (u16*)(ws + 89662464);    // v, later f2 high half
  u16*   vTbuf = (u16*)(ws + 114828288);   // v^T, dead after attn
  const size_t base_end = 139994112;       // end of vTbuf
  float* f2    = (float*)kbuf;             // 16384*768 fp32 (aliases k+v, both dead)
  float* x1    = (float*)d_out;            // x + attn proj (fp32), finalized in place

  // f1 (GELU out, bf16 [M][3072]) placement: full-size after vTbuf if ws
  // allows, else alias the dead vbuf+vTbuf region and chunk the FFN over
  // token rows (multiples of 128). Deterministic in ws_size -> capture-safe.
  const size_t f1_full = (size_t)NBS * NF * 2;   // 100,663,296
  u16* f1buf;
  int mc;                                         // rows per FFN chunk
  if (ws_size >= base_end + f1_full) {
    f1buf = (u16*)(ws + base_end);
    mc = NBS;
  } else {
    f1buf = vbuf;                                 // [89.7M, 140M) = 50.3MB free at FFN time
    size_t cap = (ws_size < base_end ? ws_size : base_end) - 89662464;
    mc = (int)(cap / ((size_t)NF * 2)) / 128 * 128;
    if (mc <= 0) mc = 128;                        // ws hopelessly small; best effort
    if (mc > NBS) mc = NBS;
  }

  // weight packing (weights re-poisoned every call -> repack every call)
  pack_qkv<<<dim3(36, 12), 256, 0, stream>>>(Wq, Wk, Wv, bq, bk, bv, WqkvT, qkvb);
  pack_t  <<<dim3(NE/64, NE/64), 256, 0, stream>>>(Wp, WpT, NE, NE);
  pack_t  <<<dim3(NF/64, NE/64), 256, 0, stream>>>(W1, W1T, NF, NE);
  pack_t  <<<dim3(NE/64, NF/64), 256, 0, stream>>>(W2, W2T, NE, NF);

  ln_bf16<<<NBS, 256, 0, stream>>>(x, g1, b1n, hbuf);
  gemm_bt<0><<<dim3(2304/128, NBS/128), 256, 0, stream>>>(hbuf, WqkvT, qkvb, nullptr,
      nullptr, nullptr, qbuf, kbuf, vbuf, NBS, 2304, NE);
  transpose_v<<<dim3(NS/64, NBH), 256, 0, stream>>>(vbuf, vTbuf);
  attn<<<dim3(NS/128, NBH), 256, 0, stream>>>(qbuf, kbuf, vTbuf, hbuf);
  gemm_bt<1><<<dim3(NE/128, NBS/128), 256, 0, stream>>>(hbuf, WpT, bp, x,
      x1, nullptr, nullptr, nullptr, nullptr, NBS, NE, NE);
  ln_bf16<<<NBS, 256, 0, stream>>>(x1, g2, b2n, qbuf);
  for (int r0 = 0; r0 < NBS; r0 += mc) {
    int m = (NBS - r0 < mc) ? (NBS - r0) : mc;
    gemm_bt<2><<<dim3(NF/128, m/128), 256, 0, stream>>>(qbuf + (size_t)r0*NE, W1T, b1f,
        nullptr, nullptr, f1buf, nullptr, nullptr, nullptr, m, NF, NE);
    gemm_bt<3><<<dim3(NE/128, m/128), 256, 0, stream>>>(f1buf, W2T, b2f, nullptr,
        f2 + (size_t)r0*NE, nullptr, nullptr, nullptr, nullptr, m, NE, NF);
  }
  ln_add_out<<<NBS, 256, 0, stream>>>(f2, gf, bf, x1);
}

// Round 7
// 655.521 us; speedup vs baseline: 1.1095x; 1.0792x over previous
//
#include <hip/hip_runtime.h>
#include <math.h>

typedef unsigned short u16;
typedef __attribute__((ext_vector_type(8))) short s16x8;   // 8 bf16 (4 VGPRs) MFMA A/B frag
typedef __attribute__((ext_vector_type(4))) float f32x4;   // MFMA C/D frag

#define NB 16
#define NS 1024
#define NE 768
#define NH 12
#define ND 64
#define NF 3072
#define NBS (NB*NS)   // 16384 token rows
#define NBH (NB*NH)   // 192 (b,h) pairs

__device__ __forceinline__ u16 f2bf(float f){
  unsigned u = __float_as_uint(f);
  unsigned r = (u + 0x7fffu + ((u >> 16) & 1u)) >> 16;  // RNE
  return (u16)r;
}

__device__ __forceinline__ void gload16(const void* g, void* l){
  // async global->LDS, 16B per lane; LDS dest = wave-uniform base + lane*16
  __builtin_amdgcn_global_load_lds((const __attribute__((address_space(1))) void*)g,
                                   (__attribute__((address_space(3))) void*)l, 16, 0, 0);
}

// ---------------- weight packing: fp32 [K][N] -> bf16 [N][K] (B^T for GEMM) ---
__global__ __launch_bounds__(256) void pack_t(const float* __restrict__ W,
                                              u16* __restrict__ Wt, int N, int K){
  __shared__ u16 tile[64*72];
  const int tid = threadIdx.x;
  const int n0 = blockIdx.x*64, k0 = blockIdx.y*64;
  #pragma unroll
  for (int it = 0; it < 4; ++it){
    int c = it*256 + tid;
    int row = c >> 4, col = (c & 15) * 4;        // row = k-local, col = n-local
    float4 v = *(const float4*)(W + (size_t)(k0+row)*N + n0 + col);
    tile[row*72+col+0] = f2bf(v.x); tile[row*72+col+1] = f2bf(v.y);
    tile[row*72+col+2] = f2bf(v.z); tile[row*72+col+3] = f2bf(v.w);
  }
  __syncthreads();
  #pragma unroll
  for (int it = 0; it < 2; ++it){
    int c = it*256 + tid;
    int nr = c >> 3, kc = (c & 7) * 8;
    s16x8 val;
    #pragma unroll
    for (int j = 0; j < 8; ++j) val[j] = tile[(kc+j)*72 + nr];
    *(s16x8*)(Wt + (size_t)(n0+nr)*K + k0 + kc) = val;
  }
}

// Wq/Wk/Wv are [H,E,D]; pack into [2304][768] bf16 rows n = p*768 + h*64 + d.
__global__ __launch_bounds__(256) void pack_qkv(const float* __restrict__ Wq,
    const float* __restrict__ Wk, const float* __restrict__ Wv,
    const float* __restrict__ bq, const float* __restrict__ bk,
    const float* __restrict__ bv, u16* __restrict__ Wt, float* __restrict__ bias){
  __shared__ u16 tile[64*72];
  const int tid = threadIdx.x;
  const int n0 = blockIdx.x*64, e0 = blockIdx.y*64;
  const int p = n0 / NE, rr = n0 % NE, h = rr >> 6;   // 64-wide tile = one head
  const float* Wsrc = (p==0) ? Wq : ((p==1) ? Wk : Wv);
  #pragma unroll
  for (int it = 0; it < 4; ++it){
    int c = it*256 + tid;
    int row = c >> 4, col = (c & 15) * 4;        // row = e-local, col = d
    float4 v = *(const float4*)(Wsrc + ((size_t)h*NE + e0 + row)*ND + col);
    tile[row*72+col+0] = f2bf(v.x); tile[row*72+col+1] = f2bf(v.y);
    tile[row*72+col+2] = f2bf(v.z); tile[row*72+col+3] = f2bf(v.w);
  }
  __syncthreads();
  #pragma unroll
  for (int it = 0; it < 2; ++it){
    int c = it*256 + tid;
    int dr = c >> 3, ec = (c & 7) * 8;
    s16x8 val;
    #pragma unroll
    for (int j = 0; j < 8; ++j) val[j] = tile[(ec+j)*72 + dr];
    *(s16x8*)(Wt + (size_t)(n0+dr)*NE + e0 + ec) = val;
  }
  if (e0 == 0 && tid < 64){
    const float* bsrc = (p==0) ? bq : ((p==1) ? bk : bv);
    bias[n0 + tid] = bsrc[rr + tid];
  }
}

// ---------------- LayerNorm: fp32 in -> bf16 out (row = 768) -----------------
__global__ __launch_bounds__(256) void ln_bf16(const float* __restrict__ x,
    const float* __restrict__ g, const float* __restrict__ b, u16* __restrict__ out){
  __shared__ float red[4];
  const int row = blockIdx.x, tid = threadIdx.x;
  const float* xr = x + (size_t)row*NE;
  float v0 = xr[tid], v1 = xr[tid+256], v2 = xr[tid+512];
  float s = v0 + v1 + v2;
  #pragma unroll
  for (int off = 32; off > 0; off >>= 1) s += __shfl_down(s, off);
  if ((tid & 63) == 0) red[tid >> 6] = s;
  __syncthreads();
  float mu = (red[0]+red[1]+red[2]+red[3]) * (1.f/NE);
  float d0 = v0-mu, d1 = v1-mu, d2 = v2-mu;
  float q = d0*d0 + d1*d1 + d2*d2;
  #pragma unroll
  for (int off = 32; off > 0; off >>= 1) q += __shfl_down(q, off);
  __syncthreads();
  if ((tid & 63) == 0) red[tid >> 6] = q;
  __syncthreads();
  float rs = rsqrtf((red[0]+red[1]+red[2]+red[3]) * (1.f/NE) + 1e-5f);
  u16* orow = out + (size_t)row*NE;
  orow[tid]     = f2bf(d0*rs*g[tid]     + b[tid]);
  orow[tid+256] = f2bf(d1*rs*g[tid+256] + b[tid+256]);
  orow[tid+512] = f2bf(d2*rs*g[tid+512] + b[tid+512]);
}

// final: out = x1 + LN(f2) (in-place on x1 == d_out, fp32)
__global__ __launch_bounds__(256) void ln_add_out(const float* __restrict__ f2,
    const float* __restrict__ g, const float* __restrict__ b, float* __restrict__ x1){
  __shared__ float red[4];
  const int row = blockIdx.x, tid = threadIdx.x;
  const float* xr = f2 + (size_t)row*NE;
  float v0 = xr[tid], v1 = xr[tid+256], v2 = xr[tid+512];
  float s = v0 + v1 + v2;
  #pragma unroll
  for (int off = 32; off > 0; off >>= 1) s += __shfl_down(s, off);
  if ((tid & 63) == 0) red[tid >> 6] = s;
  __syncthreads();
  float mu = (red[0]+red[1]+red[2]+red[3]) * (1.f/NE);
  float d0 = v0-mu, d1 = v1-mu, d2 = v2-mu;
  float q = d0*d0 + d1*d1 + d2*d2;
  #pragma unroll
  for (int off = 32; off > 0; off >>= 1) q += __shfl_down(q, off);
  __syncthreads();
  if ((tid & 63) == 0) red[tid >> 6] = q;
  __syncthreads();
  float rs = rsqrtf((red[0]+red[1]+red[2]+red[3]) * (1.f/NE) + 1e-5f);
  float* orow = x1 + (size_t)row*NE;
  orow[tid]     += d0*rs*g[tid]     + b[tid];
  orow[tid+256] += d1*rs*g[tid+256] + b[tid+256];
  orow[tid+512] += d2*rs*g[tid+512] + b[tid+512];
}

// ---------------- generic bf16 MFMA GEMM: C[M][N] = A[M][K] * Bt[N][K]^T -----
// 128x128 tile, 4 waves (2x2), BK=32, global_load_lds staging (m97 structure).
// EPI: 0 = QKV scatter (+bias, K pre-scaled by log2e/sqrt(D)), 1 = +bias+resid
//      fp32, 2 = +bias GELU bf16, 3 = +bias fp32
template<int EPI>
__global__ __launch_bounds__(256, 2)
void gemm_bt(const u16* __restrict__ A, const u16* __restrict__ Bt,
             const float* __restrict__ bias, const float* __restrict__ resid,
             float* __restrict__ outF, u16* __restrict__ outU,
             u16* __restrict__ oq, u16* __restrict__ ok, u16* __restrict__ ov,
             int M, int N, int K)
{
  __shared__ u16 As[128*32];
  __shared__ u16 Bs[128*32];
  const int tid = threadIdx.x;
  const int lane = tid & 63, wv = tid >> 6;
  const int wm = wv >> 1, wn = wv & 1;
  const int r = lane & 15, g4 = lane >> 4;
  const int m0 = blockIdx.y*128, n0 = blockIdx.x*128;

  f32x4 acc[4][4] = {};

  for (int kt = 0; kt < K; kt += 32) {
    __syncthreads();
    #pragma unroll
    for (int it = 0; it < 2; ++it) {
      int c = it*256 + tid;
      int row = c >> 2, kc = (c & 3) << 3;         // 4 chunks of 8 bf16 per row
      gload16(A  + (size_t)(m0+row)*K + kt + kc, As + (size_t)(it*256 + wv*64)*8);
      gload16(Bt + (size_t)(n0+row)*K + kt + kc, Bs + (size_t)(it*256 + wv*64)*8);
    }
    __syncthreads();
    s16x8 aF[4], bF[4];
    #pragma unroll
    for (int mi = 0; mi < 4; ++mi)
      aF[mi] = *(const s16x8*)(As + (wm*64 + mi*16 + r)*32 + g4*8);
    #pragma unroll
    for (int ni = 0; ni < 4; ++ni)
      bF[ni] = *(const s16x8*)(Bs + (wn*64 + ni*16 + r)*32 + g4*8);
    #pragma unroll
    for (int mi = 0; mi < 4; ++mi)
      #pragma unroll
      for (int ni = 0; ni < 4; ++ni)
        acc[mi][ni] = __builtin_amdgcn_mfma_f32_16x16x32_bf16(aF[mi], bF[ni], acc[mi][ni], 0, 0, 0);
  }

  const int colb = n0 + wn*64, rowb = m0 + wm*64;
  #pragma unroll
  for (int mi = 0; mi < 4; ++mi) {
    #pragma unroll
    for (int ni = 0; ni < 4; ++ni) {
      const int col = colb + ni*16 + r;
      const float bv = bias[col];
      #pragma unroll
      for (int i = 0; i < 4; ++i) {
        const int row = rowb + mi*16 + g4*4 + i;   // C/D: col=lane&15, row=(lane>>4)*4+i
        float v = acc[mi][ni][i] + bv;
        if (EPI == 0) {
          int p = col / NE, rr2 = col % NE;
          int hh = rr2 >> 6, d = rr2 & 63;
          int bb = row >> 10, ss = row & (NS-1);
          size_t idx = (((size_t)(bb*NH + hh))*NS + ss)*ND + d;
          if (p == 1) v *= 0.18033688011112042f;   // log2(e)/sqrt(D) folded into K
          u16 val = f2bf(v);
          if (p == 0) oq[idx] = val;
          else if (p == 1) ok[idx] = val;
          else ov[idx] = val;
        } else if (EPI == 1) {
          size_t idx = (size_t)row*NE + col;
          outF[idx] = resid[idx] + v;
        } else if (EPI == 2) {
          float ge = 0.5f * v * (1.0f + erff(v * 0.70710678118654752f));
          outU[(size_t)row*NF + col] = f2bf(ge);
        } else {
          outF[(size_t)row*NE + col] = v;
        }
      }
    }
  }
}

// ---------------- v [BH][S][D] -> vT [BH][D][S] (bf16) -----------------------
__global__ __launch_bounds__(256) void transpose_v(const u16* __restrict__ v,
                                                   u16* __restrict__ vT){
  __shared__ u16 tile[64*80];
  const int tid = threadIdx.x;
  const int t0 = blockIdx.x*64, bh = blockIdx.y;
  const u16* src = v + ((size_t)bh*NS + t0)*ND;
  #pragma unroll
  for (int it = 0; it < 2; ++it){
    int c = it*256 + tid;
    int row = c >> 3, col = (c & 7) * 8;
    *(s16x8*)(tile + row*80 + col) = *(const s16x8*)(src + (size_t)row*ND + col);
  }
  __syncthreads();
  u16* dst = vT + (size_t)bh*ND*NS + t0;
  #pragma unroll
  for (int it = 0; it < 2; ++it){
    int c = it*256 + tid;
    int d = c >> 3, tc = (c & 7) * 8;
    s16x8 val;
    #pragma unroll
    for (int j = 0; j < 8; ++j) val[j] = tile[(tc+j)*80 + d];
    *(s16x8*)(dst + (size_t)d*NS + tc) = val;
  }
}

// ---------------- flash attention (causal) -----------------------------------
// v4: causal PAIRING for load balance — block handles q-tiles (qt, 15-qt) as
//     its two 64-row groups => uniform 17 tile-participations per block
//     (was 3..31). Plus T13 defer-max. Inner code = v3 (stride 80, 2 barriers,
//     exp2 softmax with scale folded into K, XCD swizzle, setprio).
__global__ __launch_bounds__(256, 2)
void attn(const u16* __restrict__ q, const u16* __restrict__ k,
          const u16* __restrict__ vT, u16* __restrict__ o)
{
  __shared__ u16 Ks[64*80];   // K tile  [t][d]
  __shared__ u16 Vs[64*80];   // V^T tile [d][t]
  __shared__ u16 Ps[64*80];   // P tile  [s][t] bf16 (wave-private rows)
  const int tid = threadIdx.x, lane = tid & 63, w = tid >> 6;
  const int r = lane & 15, g4 = lane >> 4;
  // XCD swizzle: physical -> logical (bh-major), 192-block chunks per XCD so
  // all 8 pair-blocks of a (b,h) share one XCD's L2. 1536 % 8 == 0.
  const int phys = blockIdx.y * 8 + blockIdx.x;     // gridDim = (8, 192)
  const int logical = (phys & 7) * 192 + (phys >> 3);
  const int bh = logical >> 3, qt = logical & 7;    // pair = (qt, 15-qt)
  const int bb = bh / NH, hh = bh % NH;
  const int rgb0 = qt * 64, rgb1 = (15 - qt) * 64;  // rowgroup bases

  s16x8 qf[2][2];
  {
    const u16* qb = q + ((size_t)bh*NS + w*16 + r)*ND;
    qf[0][0] = *(const s16x8*)(qb + (size_t)rgb0*ND + g4*8);
    qf[0][1] = *(const s16x8*)(qb + (size_t)rgb0*ND + 32 + g4*8);
    qf[1][0] = *(const s16x8*)(qb + (size_t)rgb1*ND + g4*8);
    qf[1][1] = *(const s16x8*)(qb + (size_t)rgb1*ND + 32 + g4*8);
  }

  f32x4 oacc[2][4] = {};
  float mrow[2][4], lrow[2][4];
  #pragma unroll
  for (int rg = 0; rg < 2; ++rg)
    #pragma unroll
    for (int i = 0; i < 4; ++i){ mrow[rg][i] = -INFINITY; lrow[rg][i] = 0.f; }

  const u16* kbase = k  + (size_t)bh*NS*ND;
  const u16* vbase = vT + (size_t)bh*ND*NS;
  const int nt = 16 - qt;                           // tiles 0 .. 15-qt

  for (int t = 0; t < nt; ++t) {
    const int kt0 = t*64;
    __syncthreads();
    #pragma unroll
    for (int it = 0; it < 2; ++it) {
      int c = it*256 + tid;
      int rowi = c >> 3, coli = (c & 7) * 8;
      *(s16x8*)(Ks + rowi*80 + coli) = *(const s16x8*)(kbase + (size_t)(kt0+rowi)*ND + coli);
      *(s16x8*)(Vs + rowi*80 + coli) = *(const s16x8*)(vbase + (size_t)rowi*NS + kt0 + coli);
    }
    __syncthreads();

    #pragma unroll
    for (int rg = 0; rg < 2; ++rg) {
      const int rgb = (rg == 0) ? rgb0 : rgb1;
      if (kt0 > rgb) continue;               // fully masked (uniform branch)

      f32x4 sc[4];
      __builtin_amdgcn_s_setprio(1);
      #pragma unroll
      for (int ni = 0; ni < 4; ++ni) {
        s16x8 kf0 = *(const s16x8*)(Ks + (ni*16+r)*80 + g4*8);
        s16x8 kf1 = *(const s16x8*)(Ks + (ni*16+r)*80 + 32 + g4*8);
        f32x4 tacc = {};
        tacc = __builtin_amdgcn_mfma_f32_16x16x32_bf16(qf[rg][0], kf0, tacc, 0, 0, 0);
        tacc = __builtin_amdgcn_mfma_f32_16x16x32_bf16(qf[rg][1], kf1, tacc, 0, 0, 0);
        sc[ni] = tacc;
      }
      __builtin_amdgcn_s_setprio(0);

      float mx[4];
      #pragma unroll
      for (int i = 0; i < 4; ++i) mx[i] = mrow[rg][i];
      if (kt0 == rgb) {                       // diagonal tile: causal mask
        #pragma unroll
        for (int ni = 0; ni < 4; ++ni)
          #pragma unroll
          for (int i = 0; i < 4; ++i) {
            if (ni*16 + r > w*16 + g4*4 + i) sc[ni][i] = -INFINITY;
            mx[i] = fmaxf(mx[i], sc[ni][i]);
          }
      } else {
        #pragma unroll
        for (int ni = 0; ni < 4; ++ni)
          #pragma unroll
          for (int i = 0; i < 4; ++i) mx[i] = fmaxf(mx[i], sc[ni][i]);
      }
      #pragma unroll
      for (int i = 0; i < 4; ++i) {
        #pragma unroll
        for (int off = 1; off < 16; off <<= 1) mx[i] = fmaxf(mx[i], __shfl_xor(mx[i], off));
      }
      // T13 defer-max: skip the O/l rescale when max growth <= 8 (exact math,
      // P bounded by 2^8; -inf initial mrow forces the rescale on first tile)
      bool nogrow = true;
      #pragma unroll
      for (int i = 0; i < 4; ++i) nogrow = nogrow && (mx[i] - mrow[rg][i] <= 8.f);
      float psum[4];
      if (!__all(nogrow)) {
        #pragma unroll
        for (int i = 0; i < 4; ++i) {
          float corr = exp2f(mrow[rg][i] - mx[i]);  // exp2(-inf)=0 on first tile
          mrow[rg][i] = mx[i];
          lrow[rg][i] *= corr;
          #pragma unroll
          for (int di = 0; di < 4; ++di) oacc[rg][di][i] *= corr;
        }
      }
      #pragma unroll
      for (int ni = 0; ni < 4; ++ni)
        #pragma unroll
        for (int i = 0; i < 4; ++i) {
          float p = exp2f(sc[ni][i] - mrow[rg][i]);   // scores already log2-scaled
          if (ni == 0) psum[i] = p; else psum[i] += p;
          Ps[(w*16 + g4*4 + i)*80 + ni*16 + r] = f2bf(p);
        }
      #pragma unroll
      for (int i = 0; i < 4; ++i) {
        #pragma unroll
        for (int off = 1; off < 16; off <<= 1) psum[i] += __shfl_xor(psum[i], off);
        lrow[rg][i] += psum[i];
      }
      // PV (wave reads only its own 16 Ps rows; same-wave in-order LDS dep)
      __builtin_amdgcn_s_setprio(1);
      #pragma unroll
      for (int kk = 0; kk < 2; ++kk) {
        s16x8 pf = *(const s16x8*)(&Ps[(w*16 + r)*80 + kk*32 + g4*8]);
        #pragma unroll
        for (int di = 0; di < 4; ++di) {
          s16x8 vf = *(const s16x8*)(&Vs[(di*16+r)*80 + kk*32 + g4*8]);
          oacc[rg][di] = __builtin_amdgcn_mfma_f32_16x16x32_bf16(pf, vf, oacc[rg][di], 0, 0, 0);
        }
      }
      __builtin_amdgcn_s_setprio(0);
    }
  }

  #pragma unroll
  for (int rg = 0; rg < 2; ++rg) {
    const int rgb = (rg == 0) ? rgb0 : rgb1;
    #pragma unroll
    for (int i = 0; i < 4; ++i) {
      float inv = 1.f / lrow[rg][i];
      int s = rgb + w*16 + g4*4 + i;
      u16* orow = o + ((size_t)(bb*NS + s))*NE + hh*ND;
      #pragma unroll
      for (int di = 0; di < 4; ++di)
        orow[di*16 + r] = f2bf(oacc[rg][di][i] * inv);
    }
  }
}

// ---------------- launch ------------------------------------------------------
extern "C" void kernel_launch(void* const* d_in, const int* in_sizes, int n_in,
                              void* d_out, int out_size, void* d_ws, size_t ws_size,
                              hipStream_t stream)
{
  const float* x   = (const float*)d_in[0];
  const float* Wq  = (const float*)d_in[1];
  const float* bq  = (const float*)d_in[2];
  const float* Wk  = (const float*)d_in[3];
  const float* bk  = (const float*)d_in[4];
  const float* Wv  = (const float*)d_in[5];
  const float* bv  = (const float*)d_in[6];
  const float* Wp  = (const float*)d_in[7];
  const float* bp  = (const float*)d_in[8];
  const float* g1  = (const float*)d_in[9];
  const float* b1n = (const float*)d_in[10];
  const float* g2  = (const float*)d_in[11];
  const float* b2n = (const float*)d_in[12];
  const float* W1  = (const float*)d_in[13];
  const float* b1f = (const float*)d_in[14];
  const float* W2  = (const float*)d_in[15];
  const float* b2f = (const float*)d_in[16];
  const float* gf  = (const float*)d_in[17];
  const float* bf  = (const float*)d_in[18];

  char* ws = (char*)d_ws;
  u16*   WqkvT = (u16*)(ws + 0);           // 2304*768 bf16
  u16*   WpT   = (u16*)(ws + 3538944);     // 768*768
  u16*   W1T   = (u16*)(ws + 4718592);     // 3072*768
  u16*   W2T   = (u16*)(ws + 9437184);     // 768*3072
  float* qkvb  = (float*)(ws + 14155776);  // 2304 fp32
  u16*   hbuf  = (u16*)(ws + 14164992);    // h (LN1), later o
  u16*   qbuf  = (u16*)(ws + 39330816);    // q, later h2
  u16*   kbuf  = (u16*)(ws + 64496640);    // k, later f2 low half
  u16*   vbuf  = (u16*)(ws + 89662464);    // v, later f2 high half
  u16*   vTbuf = (u16*)(ws + 114828288);   // v^T, dead after attn
  const size_t base_end = 139994112;       // end of vTbuf
  float* f2    = (float*)kbuf;             // 16384*768 fp32 (aliases k+v, both dead)
  float* x1    = (float*)d_out;            // x + attn proj (fp32), finalized in place

  // f1 (GELU out, bf16 [M][3072]) placement: full-size after vTbuf if ws
  // allows, else alias the dead vbuf+vTbuf region and chunk the FFN over
  // token rows (multiples of 128). Deterministic in ws_size -> capture-safe.
  const size_t f1_full = (size_t)NBS * NF * 2;   // 100,663,296
  u16* f1buf;
  int mc;                                         // rows per FFN chunk
  if (ws_size >= base_end + f1_full) {
    f1buf = (u16*)(ws + base_end);
    mc = NBS;
  } else {
    f1buf = vbuf;                                 // [89.7M, 140M) = 50.3MB free at FFN time
    size_t cap = (ws_size < base_end ? ws_size : base_end) - 89662464;
    mc = (int)(cap / ((size_t)NF * 2)) / 128 * 128;
    if (mc <= 0) mc = 128;                        // ws hopelessly small; best effort
    if (mc > NBS) mc = NBS;
  }

  // weight packing (weights re-poisoned every call -> repack every call)
  pack_qkv<<<dim3(36, 12), 256, 0, stream>>>(Wq, Wk, Wv, bq, bk, bv, WqkvT, qkvb);
  pack_t  <<<dim3(NE/64, NE/64), 256, 0, stream>>>(Wp, WpT, NE, NE);
  pack_t  <<<dim3(NF/64, NE/64), 256, 0, stream>>>(W1, W1T, NF, NE);
  pack_t  <<<dim3(NE/64, NF/64), 256, 0, stream>>>(W2, W2T, NE, NF);

  ln_bf16<<<NBS, 256, 0, stream>>>(x, g1, b1n, hbuf);
  gemm_bt<0><<<dim3(2304/128, NBS/128), 256, 0, stream>>>(hbuf, WqkvT, qkvb, nullptr,
      nullptr, nullptr, qbuf, kbuf, vbuf, NBS, 2304, NE);
  transpose_v<<<dim3(NS/64, NBH), 256, 0, stream>>>(vbuf, vTbuf);
  attn<<<dim3(8, NBH), 256, 0, stream>>>(qbuf, kbuf, vTbuf, hbuf);
  gemm_bt<1><<<dim3(NE/128, NBS/128), 256, 0, stream>>>(hbuf, WpT, bp, x,
      x1, nullptr, nullptr, nullptr, nullptr, NBS, NE, NE);
  ln_bf16<<<NBS, 256, 0, stream>>>(x1, g2, b2n, qbuf);
  for (int r0 = 0; r0 < NBS; r0 += mc) {
    int m = (NBS - r0 < mc) ? (NBS - r0) : mc;
    gemm_bt<2><<<dim3(NF/128, m/128), 256, 0, stream>>>(qbuf + (size_t)r0*NE, W1T, b1f,
        nullptr, nullptr, f1buf, nullptr, nullptr, nullptr, m, NF, NE);
    gemm_bt<3><<<dim3(NE/128, m/128), 256, 0, stream>>>(f1buf, W2T, b2f, nullptr,
        f2 + (size_t)r0*NE, nullptr, nullptr, nullptr, nullptr, m, NE, NF);
  }
  ln_add_out<<<NBS, 256, 0, stream>>>(f2, gf, bf, x1);
}